// Round 9
// baseline (28.611 us; speedup 1.0000x reference)
//
#include <hip/hip_runtime.h>

// TensorizedAutoencoder: B=2048, D=512, H=128, K=16, f32 in/out.
// R9: two mechanism-targeted edits on the passing R8 structure:
//  (a) spill-safe weight pipelining: 32-float (4-kstep) alternating batch
//      buffers, hand-unrolled -> ~64 transient VGPRs (R8's 128-float batches
//      likely spilled, explaining its -1.1us vs predicted -9).
//  (b) xc fragment pass-through: assign_k writes hi/lo bf16 A-fragments to ws
//      (lane l == frag slot (s=l>>2,g=l&3); all lanes know bestk after the
//      butterfly). ae_k enc staging becomes 2 int4 loads/slot.
// MFMA order/operands bit-identical to R8 -> absmax must stay 0.03125.

#define BB 2048
#define DD 512
#define HH 128
#define KK 16
#define MAXTILES 143   // max sum of ceil(cnt_k/16) = 128 + 15

typedef float f4v __attribute__((ext_vector_type(4)));
typedef short s8v __attribute__((ext_vector_type(8)));

union U4 { uint4 u; int4 i; s8v v; };

__device__ inline uint pk2(float a, float b) {   // {bf16(a), bf16(b)} packed
    uint r;
    asm("v_cvt_pk_bf16_f32 %0, %1, %2" : "=v"(r) : "v"(a), "v"(b));
    return r;
}
__device__ inline void split2(float a, float b, uint& hi, uint& lo) {
    hi = pk2(a, b);
    const float ha = __uint_as_float(hi << 16);
    const float hb = __uint_as_float(hi & 0xffff0000u);
    lo = pk2(a - ha, b - hb);                    // residual: split self-corrects
}
__device__ inline U4 packrow(const float* bl) {
    U4 r;
    r.u = make_uint4(pk2(bl[0], bl[1]), pk2(bl[2], bl[3]),
                     pk2(bl[4], bl[5]), pk2(bl[6], bl[7]));
    return r;
}

// ---- enc weight pipeline helpers (static indexing only) ----
__device__ inline void enc_issue(const float* __restrict__ Wp, int b0, int g,
                                 float bl[32]) {
    #pragma unroll
    for (int s4 = 0; s4 < 4; ++s4)
        #pragma unroll
        for (int j = 0; j < 8; ++j)
            bl[s4 * 8 + j] = Wp[(size_t)((b0 + s4) * 32 + g * 8 + j) * HH];
}
__device__ inline void enc_step(const int4* __restrict__ Ah,
                                const int4* __restrict__ Al, int l, int b0,
                                const float bl[32], f4v& aH, f4v& aL) {
    #pragma unroll
    for (int s4 = 0; s4 < 4; ++s4) {
        const U4 bf = packrow(&bl[s4 * 8]);
        U4 ah, al;
        ah.i = Ah[(b0 + s4) * 64 + l];
        al.i = Al[(b0 + s4) * 64 + l];
        aH = __builtin_amdgcn_mfma_f32_16x16x32_bf16(ah.v, bf.v, aH, 0, 0, 0);
        aL = __builtin_amdgcn_mfma_f32_16x16x32_bf16(al.v, bf.v, aL, 0, 0, 0);
    }
}
// ---- dec weight pipeline helpers (batch = kstep s, 4 f-frags) ----
__device__ inline void dec_issue(const float* __restrict__ Vp, int s, int g,
                                 float cl[32]) {
    #pragma unroll
    for (int f = 0; f < 4; ++f)
        #pragma unroll
        for (int j = 0; j < 8; ++j)
            cl[f * 8 + j] = Vp[(size_t)(s * 32 + g * 8 + j) * DD + f * 16];
}
__device__ inline void dec_step(const int4* __restrict__ Dh,
                                const int4* __restrict__ Dl, int l, int s,
                                const float cl[32], f4v dH[4], f4v dL[4]) {
    U4 ah, al;
    ah.i = Dh[s * 64 + l];
    al.i = Dl[s * 64 + l];
    #pragma unroll
    for (int f = 0; f < 4; ++f) {
        const U4 cf = packrow(&cl[f * 8]);
        dH[f] = __builtin_amdgcn_mfma_f32_16x16x32_bf16(ah.v, cf.v, dH[f], 0, 0, 0);
        dL[f] = __builtin_amdgcn_mfma_f32_16x16x32_bf16(al.v, cf.v, dL[f], 0, 0, 0);
    }
}

__global__ __launch_bounds__(256) void assign_k(const float* __restrict__ x,
                                                const float* __restrict__ c,
                                                int* __restrict__ idx,
                                                int4* __restrict__ xcf) {
    const int lane = threadIdx.x & 63;
    const int row = (blockIdx.x << 2) + (threadIdx.x >> 6);
    if (row >= BB) return;

    const float4* x4 = reinterpret_cast<const float4*>(x + (size_t)row * DD);
    const float4 xa = x4[lane * 2];
    const float4 xb = x4[lane * 2 + 1];

    float bestd = 3.4e38f;
    int bestk = 0;
    for (int k = 0; k < KK; ++k) {
        const float4* c4 = reinterpret_cast<const float4*>(c + (size_t)k * DD);
        const float4 ca = c4[lane * 2];
        const float4 cb = c4[lane * 2 + 1];
        float dotv = xa.x * ca.x + xa.y * ca.y + xa.z * ca.z + xa.w * ca.w
                   + xb.x * cb.x + xb.y * cb.y + xb.z * cb.z + xb.w * cb.w;
        float cc = ca.x * ca.x + ca.y * ca.y + ca.z * ca.z + ca.w * ca.w
                 + cb.x * cb.x + cb.y * cb.y + cb.z * cb.z + cb.w * cb.w;
        float v = cc - 2.0f * dotv;   // ||x||^2 constant across k (argmin-invariant)
        #pragma unroll
        for (int off = 32; off > 0; off >>= 1) v += __shfl_xor(v, off, 64);
        if (v < bestd) { bestd = v; bestk = k; }   // strict < keeps first-min
    }
    if (lane == 0) idx[row] = bestk;

    // ---- pass-through: write hi/lo bf16 xc fragment (slot s=lane>>2,g=lane&3)
    // All lanes hold identical bestk (butterfly left full sums everywhere).
    {
        const float4* c4 = reinterpret_cast<const float4*>(c + (size_t)bestk * DD);
        const float4 ca = c4[lane * 2];
        const float4 cb = c4[lane * 2 + 1];
        U4 H, L;
        split2(xa.x - ca.x, xa.y - ca.y, H.u.x, L.u.x);
        split2(xa.z - ca.z, xa.w - ca.w, H.u.y, L.u.y);
        split2(xb.x - cb.x, xb.y - cb.y, H.u.z, L.u.z);
        split2(xb.z - cb.z, xb.w - cb.w, H.u.w, L.u.w);
        int4* dst = xcf + (size_t)row * 128 + lane * 2;   // 32 B/lane coalesced
        dst[0] = H.i;
        dst[1] = L.i;
    }
}

// Fragment conventions (mfma_f32_16x16x32_bf16, lane l, g=l>>4):
//   A: row=l&15, k=8g+j   B: k=8g+j, col=l&15   D: col=l&15, row=4g+reg [m89]
__global__ __launch_bounds__(512) void ae_k(const float* __restrict__ encW,
                                            const float* __restrict__ encB,
                                            const float* __restrict__ decW,
                                            const float* __restrict__ decB,
                                            const int* __restrict__ idx,
                                            const int4* __restrict__ xcf,
                                            float* __restrict__ out) {
    __shared__ int4 frag[2048];          // 32 KB: enc A / dec A frags
    __shared__ ushort hist2[KK][512];    // 16 KB: transposed hist (2-way max)
    __shared__ float e_s[16][132];       // 8.25 KB
    __shared__ int rs_s[16];
    __shared__ ushort cnt_s[KK];
    __shared__ ushort tb_s[KK + 1];

    const int tid = threadIdx.x;
    const int b = blockIdx.x;
    const int w = tid >> 6, l = tid & 63;
    const int r16 = l & 15, g = l >> 4;

    // ---- phase 0: per-thread cluster counts, transposed layout ----
    const int4 my = *reinterpret_cast<const int4*>(idx + tid * 4);
    if (tid < 16) rs_s[tid] = -1;
    #pragma unroll
    for (int k = 0; k < KK; ++k) {
        hist2[k][tid] = (ushort)((my.x == k) + (my.y == k)
                               + (my.z == k) + (my.w == k));
    }
    __syncthreads();

    // wave w scans clusters 2w, 2w+1 over thread-order (lane l owns t=8l..8l+7)
    #pragma unroll
    for (int kk = 0; kk < 2; ++kk) {
        const int k = w * 2 + kk;
        int v[8], s = 0;
        #pragma unroll
        for (int i = 0; i < 8; ++i) { v[i] = hist2[k][l * 8 + i]; s += v[i]; }
        int sc = s;
        #pragma unroll
        for (int off = 1; off < 64; off <<= 1) {
            const int u = __shfl_up(sc, off, 64);
            if (l >= off) sc += u;
        }
        int e = sc - s;                  // exclusive start for t = 8l
        #pragma unroll
        for (int i = 0; i < 8; ++i) { hist2[k][l * 8 + i] = (ushort)e; e += v[i]; }
        if (l == 63) cnt_s[k] = (ushort)sc;
    }
    __syncthreads();
    if (tid == 0) {
        int ta = 0;
        for (int k = 0; k < KK; ++k) { tb_s[k] = (ushort)ta; ta += (cnt_s[k] + 15) >> 4; }
        tb_s[KK] = (ushort)ta;
    }
    __syncthreads();
    if (b >= (int)tb_s[KK]) return;      // uniform exit
    int km = 0;
    #pragma unroll
    for (int kk = 1; kk < KK; ++kk) if (b >= (int)tb_s[kk]) km = kk;
    const int base16 = (b - tb_s[km]) * 16;

    {   // scatter: my rows of cluster km whose rank lands in this tile
        int rank = hist2[km][tid];
        const int rv[4] = {my.x, my.y, my.z, my.w};
        #pragma unroll
        for (int i = 0; i < 4; ++i) {
            if (rv[i] == km) {
                if (rank >= base16 && rank < base16 + 16)
                    rs_s[rank - base16] = tid * 4 + i;
                rank++;
            }
        }
    }
    __syncthreads();

    // ---- issue enc weight batch 0 (ksteps 0..3) ----
    const float* Wp = encW + (size_t)km * DD * HH + w * 16 + r16;
    float blA[32], blB[32];
    enc_issue(Wp, 0, g, blA);

    // ---- stage enc A from xcf pass-through (2 slots/thread, 2 int4 each) ----
    int4* Ah = frag;                     // [16 ksteps][64 lanes]
    int4* Al = frag + 1024;
    {
        const int grow = rs_s[r16];
        const int s0 = tid >> 6;
        #pragma unroll
        for (int ss = 0; ss < 2; ++ss) {
            const int s = s0 + ss * 8;
            int4 H = make_int4(0, 0, 0, 0), L = make_int4(0, 0, 0, 0);
            if (grow >= 0) {
                const int4* p = xcf + (size_t)grow * 128 + s * 8 + g * 2;
                H = p[0];
                L = p[1];
            }
            Ah[s * 64 + l] = H;          // lane-linear: conflict-free
            Al[s * 64 + l] = L;
        }
    }
    __syncthreads();

    // ---- enc MFMA: wave w owns h-cols [16w,16w+16), K=512, 4x4-kstep pipe ----
    f4v aH = {0.f, 0.f, 0.f, 0.f}, aL = {0.f, 0.f, 0.f, 0.f};
    {
        enc_issue(Wp, 4, g, blB);
        enc_step(Ah, Al, l, 0, blA, aH, aL);
        enc_issue(Wp, 8, g, blA);
        enc_step(Ah, Al, l, 4, blB, aH, aL);
        enc_issue(Wp, 12, g, blB);
        enc_step(Ah, Al, l, 8, blA, aH, aL);
        enc_step(Ah, Al, l, 12, blB, aH, aL);

        const float bias = encB[km * HH + w * 16 + r16];
        #pragma unroll
        for (int rr = 0; rr < 4; ++rr)
            e_s[g * 4 + rr][w * 16 + r16] = fmaxf(aH[rr] + aL[rr] + bias, 0.f);
    }

    // ---- issue dec weight batch 0 (kstep 0) during e-staging ----
    const float* Vp = decW + (size_t)km * HH * DD + w * 64 + r16;
    float clA[32], clB[32];
    dec_issue(Vp, 0, g, clA);

    __syncthreads();

    // ---- stage dec A = bf16split(e) in frag layout (256 threads, 1 slot) ----
    int4* Dh = frag;                     // [4 ksteps][64 lanes] (reuse enc bufs)
    int4* Dl = frag + 256;
    if (tid < 256) {
        const int s = tid >> 6, ll = tid & 63;
        const int c0 = s * 32 + (ll >> 4) * 8;
        const float4 ea = *(const float4*)&e_s[ll & 15][c0];
        const float4 eb = *(const float4*)&e_s[ll & 15][c0 + 4];
        U4 H, L;
        split2(ea.x, ea.y, H.u.x, L.u.x);
        split2(ea.z, ea.w, H.u.y, L.u.y);
        split2(eb.x, eb.y, H.u.z, L.u.z);
        split2(eb.z, eb.w, H.u.w, L.u.w);
        Dh[s * 64 + ll] = H.i;
        Dl[s * 64 + ll] = L.i;
    }
    __syncthreads();

    // ---- dec MFMA: wave w owns d-cols [64w,64w+64) = 4 frags, K=128 ----
    f4v dH[4], dL[4];
    #pragma unroll
    for (int f = 0; f < 4; ++f) { dH[f] = (f4v){0.f,0.f,0.f,0.f}; dL[f] = (f4v){0.f,0.f,0.f,0.f}; }
    {
        dec_issue(Vp, 1, g, clB);
        dec_step(Dh, Dl, l, 0, clA, dH, dL);
        dec_issue(Vp, 2, g, clA);
        dec_step(Dh, Dl, l, 1, clB, dH, dL);
        dec_issue(Vp, 3, g, clB);
        dec_step(Dh, Dl, l, 2, clA, dH, dL);
        dec_step(Dh, Dl, l, 3, clB, dH, dL);
    }
    // ---- epilogue: + bias -> out ----
    #pragma unroll
    for (int f = 0; f < 4; ++f) {
        const int d = w * 64 + f * 16 + r16;
        const float db = decB[km * DD + d];
        #pragma unroll
        for (int rr = 0; rr < 4; ++rr) {
            const int grow = rs_s[g * 4 + rr];
            if (grow >= 0)
                out[(size_t)grow * DD + d] = dH[f][rr] + dL[f][rr] + db;
        }
    }
}

extern "C" void kernel_launch(void* const* d_in, const int* in_sizes, int n_in,
                              void* d_out, int out_size, void* d_ws, size_t ws_size,
                              hipStream_t stream) {
    const float* x       = (const float*)d_in[0];
    const float* centers = (const float*)d_in[1];
    const float* enc_W   = (const float*)d_in[2];
    const float* enc_b   = (const float*)d_in[3];
    const float* dec_W   = (const float*)d_in[4];
    const float* dec_b   = (const float*)d_in[5];
    float* out = (float*)d_out;

    // ws: [0, 8K) idx (2048 ints); [8K, 8K+4M) xc fragments (hi/lo int4 pairs)
    int*  idx = (int*)d_ws;
    int4* xcf = (int4*)((char*)d_ws + 8192);

    assign_k<<<BB / 4, 256, 0, stream>>>(x, centers, idx, xcf);
    ae_k<<<MAXTILES, 512, 0, stream>>>(enc_W, enc_b, dec_W, dec_b,
                                       idx, xcf, out);
}